// Round 1
// baseline (865.962 us; speedup 1.0000x reference)
//
#include <hip/hip_runtime.h>

// Problem constants
#define TD 128        // D
#define TS 1024       // SIZE (codes)
#define TT 2048       // T
#define TB 16         // B
#define NROWS 32768   // B*T
#define BN 128        // rows per block
#define BS 128        // codes per LDS tile
#define NT 256        // threads per block
#define EMA_W 0.99f

// d_out layout (flat fp32): [quantized BxDxT][diff][new_embedding SxD][new_usage S]
#define OFF_Q     0
#define OFF_DIFF  4194304
#define OFF_EMB   4194305
#define OFF_USAGE 4325377

__global__ void vq_zero(float* __restrict__ dout, float* __restrict__ counts) {
    int i = blockIdx.x * 256 + threadIdx.x;
    if (i < 131073) dout[OFF_DIFF + i] = 0.f;   // diff + new_embedding(region used as sums acc)
    if (i < TS) counts[i] = 0.f;
}

// e2[s] = ||embedding[s]||^2
__global__ void vq_e2(const float* __restrict__ emb, float* __restrict__ e2) {
    int s = blockIdx.x;
    int l = threadIdx.x;            // 64 threads
    const float* row = emb + (size_t)s * TD;
    float v = row[l] * row[l] + row[l + 64] * row[l + 64];
    #pragma unroll
    for (int off = 32; off; off >>= 1) v += __shfl_down(v, off, 64);
    if (l == 0) e2[s] = v;
}

__launch_bounds__(NT, 1)
__global__ void vq_main(const float* __restrict__ x,
                        const float* __restrict__ emb,
                        const float* __restrict__ e2,
                        float* __restrict__ dout,
                        float* __restrict__ counts) {
    __shared__ float xs[TD][BN];   // 64 KB: xs[d][r] = x[b][d][t0+r]
    __shared__ float es[TD][BS];   // 64 KB: es[d][c] = emb[s0+c][d]  (reused as scratch later)
    __shared__ float wsum[4];

    const int tid = threadIdx.x;
    const int blk = blockIdx.x;
    const int n0 = blk * BN;       // first row of this block
    const int b  = n0 >> 11;       // n0 / 2048
    const int t0 = n0 & (TT - 1);

    // ---- stage x tile (coalesced along t), once ----
    const float4* x4 = (const float4*)x;
    for (int k = tid; k < TD * BN / 4; k += NT) {
        int d  = k >> 5;           // /32 float4-per-row
        int r4 = k & 31;
        float4 v = x4[((size_t)b * TD + d) * (TT / 4) + (t0 >> 2) + r4];
        *(float4*)&xs[d][r4 * 4] = v;
    }

    const int tr = tid >> 4;       // 0..15 (row group)
    const int tc = tid & 15;       // 0..15 (code group)

    float bestV[8];
    int   bestI[8];
    #pragma unroll
    for (int i = 0; i < 8; i++) { bestV[i] = 3.4e38f; bestI[i] = 0; }

    for (int tile = 0; tile < TS / BS; ++tile) {
        const int s0 = tile * BS;
        __syncthreads();           // protect es from previous tile's readers
        // ---- stage embedding tile transposed: es[d][c] ----
        const float4* e4 = (const float4*)emb;
        for (int k = tid; k < BS * TD / 4; k += NT) {
            int c  = k >> 5;       // code within tile
            int d4 = k & 31;
            float4 v = e4[(size_t)(s0 + c) * (TD / 4) + d4];
            es[d4 * 4 + 0][c] = v.x;
            es[d4 * 4 + 1][c] = v.y;
            es[d4 * 4 + 2][c] = v.z;
            es[d4 * 4 + 3][c] = v.w;
        }
        __syncthreads();

        // ---- 8x8 register micro-tile over the 128-d dot ----
        float acc[8][8];
        #pragma unroll
        for (int i = 0; i < 8; i++)
            #pragma unroll
            for (int j = 0; j < 8; j++) acc[i][j] = 0.f;

        #pragma unroll 4
        for (int d = 0; d < TD; ++d) {
            float a[8], bb[8];
            *(float4*)&a[0]  = *(const float4*)&xs[d][tr * 8];
            *(float4*)&a[4]  = *(const float4*)&xs[d][tr * 8 + 4];
            *(float4*)&bb[0] = *(const float4*)&es[d][tc * 8];
            *(float4*)&bb[4] = *(const float4*)&es[d][tc * 8 + 4];
            #pragma unroll
            for (int i = 0; i < 8; i++)
                #pragma unroll
                for (int j = 0; j < 8; j++)
                    acc[i][j] = fmaf(a[i], bb[j], acc[i][j]);
        }

        // score = e2[s] - 2*dot  (x^2 is row-constant -> argmin-equivalent)
        float ev[8];
        *(float4*)&ev[0] = *(const float4*)&e2[s0 + tc * 8];
        *(float4*)&ev[4] = *(const float4*)&e2[s0 + tc * 8 + 4];
        #pragma unroll
        for (int i = 0; i < 8; i++) {
            #pragma unroll
            for (int j = 0; j < 8; j++) {
                float v = fmaf(-2.f, acc[i][j], ev[j]);
                if (v < bestV[i]) { bestV[i] = v; bestI[i] = s0 + tc * 8 + j; }
            }
        }
    }

    // ---- cross-thread argmin reduction (reuse es as scratch) ----
    __syncthreads();
    float* rv = &es[0][0];             // [128][16] floats (8 KB)
    int*   ri = (int*)&es[16][0];      // [128][16] ints   (8 KB)
    int*   cs = (int*)&es[32][0];      // [128] codes
    #pragma unroll
    for (int i = 0; i < 8; i++) {
        int r = tr * 8 + i;
        rv[r * 16 + tc] = bestV[i];
        ri[r * 16 + tc] = bestI[i];
    }
    __syncthreads();
    if (tid < BN) {
        int r = tid;
        float bv = rv[r * 16];
        int   bi = ri[r * 16];
        #pragma unroll
        for (int t2 = 1; t2 < 16; t2++) {
            float v = rv[r * 16 + t2];
            int idx = ri[r * 16 + t2];
            if (v < bv || (v == bv && idx < bi)) { bv = v; bi = idx; }
        }
        cs[r] = bi;
        atomicAdd(&counts[bi], 1.0f);
    }
    __syncthreads();

    // ---- epilogue: quantized write, diff, sums scatter ----
    const int r = tid & 127;
    const int h = tid >> 7;            // which half of D
    const int c = cs[r];
    const float4* qrow = (const float4*)(emb + (size_t)c * TD) + h * 16;
    float* sumrow = dout + OFF_EMB + (size_t)c * TD + (size_t)h * 64;
    float local = 0.f;
    #pragma unroll
    for (int k = 0; k < 16; k++) {
        float4 q4 = qrow[k];
        int d0 = h * 64 + k * 4;
        float qv[4] = {q4.x, q4.y, q4.z, q4.w};
        #pragma unroll
        for (int j = 0; j < 4; j++) {
            int d = d0 + j;
            float xv = xs[d][r];
            dout[OFF_Q + ((size_t)b * TD + d) * TT + t0 + r] = qv[j];  // coalesced in t
            float df = xv - qv[j];
            local = fmaf(df, df, local);
            atomicAdd(&sumrow[k * 4 + j], xv);
        }
    }
    // block-reduce the squared-diff partial
    #pragma unroll
    for (int off = 32; off; off >>= 1) local += __shfl_down(local, off, 64);
    int wid = tid >> 6;
    if ((tid & 63) == 0) wsum[wid] = local;
    __syncthreads();
    if (tid == 0) {
        float s2 = wsum[0] + wsum[1] + wsum[2] + wsum[3];
        atomicAdd(&dout[OFF_DIFF], s2);
    }
}

// finalize: EMA update (sums already sit in the new_embedding region), usage, diff mean
__global__ void vq_fin(const float* __restrict__ emb,
                       const float* __restrict__ usage,
                       const float* __restrict__ counts,
                       float* __restrict__ dout) {
    int g = blockIdx.x * 256 + threadIdx.x;  // 0..131071
    int s = g >> 7;
    float cnt = counts[s];
    float sum = dout[OFF_EMB + g];
    float e = emb[g];
    float target = (cnt > 0.f) ? (sum / cnt) : e;   // max(cnt,1)==cnt when cnt>0
    dout[OFF_EMB + g] = EMA_W * e + (1.f - EMA_W) * target;
    if (g < TS) dout[OFF_USAGE + g] = EMA_W * usage[g] + (1.f - EMA_W) * counts[g];
    if (g == 0) dout[OFF_DIFF] = dout[OFF_DIFF] * (1.0f / (float)(NROWS * TD));
}

extern "C" void kernel_launch(void* const* d_in, const int* in_sizes, int n_in,
                              void* d_out, int out_size, void* d_ws, size_t ws_size,
                              hipStream_t stream) {
    const float* x     = (const float*)d_in[0];
    const float* emb   = (const float*)d_in[1];
    const float* usage = (const float*)d_in[2];
    float* dout = (float*)d_out;
    float* e2     = (float*)d_ws;        // 1024 floats
    float* counts = e2 + TS;             // 1024 floats

    vq_zero<<<(131073 + 255) / 256, 256, 0, stream>>>(dout, counts);
    vq_e2<<<TS, 64, 0, stream>>>(emb, e2);
    vq_main<<<NROWS / BN, NT, 0, stream>>>(x, emb, e2, dout, counts);
    vq_fin<<<(TS * TD) / 256, 256, 0, stream>>>(emb, usage, counts, dout);
}

// Round 2
// 554.408 us; speedup vs baseline: 1.5620x; 1.5620x over previous
//
#include <hip/hip_runtime.h>

// Problem constants
#define TD 128        // D
#define TS 1024       // SIZE (codes)
#define TT 2048       // T
#define NROWS 32768   // B*T
#define BN 128        // rows per block tile
#define BS 128        // codes per LDS tile
#define NT 256        // threads per block
#define EMA_W 0.99f

// d_out layout (flat fp32): [quantized BxDxT][diff][new_embedding SxD][new_usage S]
#define OFF_Q     0
#define OFF_DIFF  4194304
#define OFF_EMB   4194305
#define OFF_USAGE 4325377

// ws layout (units: 4-byte words)
#define WS_E2      0                       // 1024 f
#define WS_COUNTS  1024                    // 1024 f
#define WS_CODES   2048                    // 32768 i
#define WS_ROWLIST 34816                   // 32768 i
#define WS_OFFS    67584                   // 1025 i
#define WS_CURSOR  68612                   // 1024 i
#define WS_EMBT    69636                   // 131072 f (16B aligned: 69636*4 % 16 == 0)
#define WS_XF      200708                  // 4194304 f (16B aligned)
#define WS_WORDS_NO_XF   (WS_XF)
#define WS_WORDS_WITH_XF (WS_XF + 4194304)

__global__ void vq_zero(float* __restrict__ dout, float* __restrict__ counts) {
    int i = threadIdx.x;   // one block of 1024
    counts[i] = 0.f;
    if (i == 0) dout[OFF_DIFF] = 0.f;
}

// per code s: e2[s] = ||emb[s]||^2 ; embT[d][s] = emb[s][d]
__global__ void vq_prep(const float* __restrict__ emb,
                        float* __restrict__ e2, float* __restrict__ embT) {
    __shared__ float red[2];
    int s = blockIdx.x, d = threadIdx.x;  // 128 threads
    float v = emb[(size_t)s * TD + d];
    embT[(size_t)d * TS + s] = v;
    float sq = v * v;
    #pragma unroll
    for (int off = 32; off; off >>= 1) sq += __shfl_down(sq, off, 64);
    if ((d & 63) == 0) red[d >> 6] = sq;
    __syncthreads();
    if (d == 0) e2[s] = red[0] + red[1];
}

template <int WRITE_XF>
__launch_bounds__(NT, 1)
__global__ void vq_main(const float* __restrict__ x,
                        const float* __restrict__ emb,
                        const float* __restrict__ embT,
                        const float* __restrict__ e2,
                        float* __restrict__ dout,
                        float* __restrict__ counts,
                        int* __restrict__ codes,
                        float* __restrict__ xf) {
    __shared__ float xs[TD][BN];   // 64 KB: xs[d][r] = x[b][d][t0+r]
    __shared__ float es[TD][BS];   // 64 KB: es[d][c] = emb[s0+c][d]; reused as scratch
    __shared__ float wsum[4];

    const int tid = threadIdx.x;
    const int n0 = blockIdx.x * BN;
    const int b  = n0 >> 11;
    const int t0 = n0 & (TT - 1);

    // ---- stage x tile (coalesced along t, contiguous per wave -> no LDS conflicts) ----
    const float4* x4 = (const float4*)x;
    for (int k = tid; k < TD * BN / 4; k += NT) {
        int d  = k >> 5;
        int r4 = k & 31;
        float4 v = x4[((size_t)b * TD + d) * (TT / 4) + (t0 >> 2) + r4];
        *(float4*)&xs[d][r4 * 4] = v;
    }

    const int tr = tid >> 4;       // 0..15
    const int tc = tid & 15;       // 0..15

    float bestV[8];
    int   bestI[8];
    #pragma unroll
    for (int i = 0; i < 8; i++) { bestV[i] = 3.4e38f; bestI[i] = 0; }

    const float4* eT4 = (const float4*)embT;
    for (int tile = 0; tile < TS / BS; ++tile) {
        const int s0 = tile * BS;
        __syncthreads();
        // ---- stage embedding tile from embT (coalesced, conflict-free) ----
        for (int k = tid; k < TD * BS / 4; k += NT) {
            int d  = k >> 5;
            int c4 = k & 31;
            float4 v = eT4[(size_t)d * (TS / 4) + (s0 >> 2) + c4];
            *(float4*)&es[d][c4 * 4] = v;
        }
        __syncthreads();

        float acc[8][8];
        #pragma unroll
        for (int i = 0; i < 8; i++)
            #pragma unroll
            for (int j = 0; j < 8; j++) acc[i][j] = 0.f;

        #pragma unroll 4
        for (int d = 0; d < TD; ++d) {
            float a[8], bb[8];
            *(float4*)&a[0]  = *(const float4*)&xs[d][tr * 8];
            *(float4*)&a[4]  = *(const float4*)&xs[d][tr * 8 + 4];
            *(float4*)&bb[0] = *(const float4*)&es[d][tc * 8];
            *(float4*)&bb[4] = *(const float4*)&es[d][tc * 8 + 4];
            #pragma unroll
            for (int i = 0; i < 8; i++)
                #pragma unroll
                for (int j = 0; j < 8; j++)
                    acc[i][j] = fmaf(a[i], bb[j], acc[i][j]);
        }

        // score = e2[s] - 2*dot (x^2 row-constant -> argmin-equivalent)
        float ev[8];
        *(float4*)&ev[0] = *(const float4*)&e2[s0 + tc * 8];
        *(float4*)&ev[4] = *(const float4*)&e2[s0 + tc * 8 + 4];
        #pragma unroll
        for (int i = 0; i < 8; i++) {
            #pragma unroll
            for (int j = 0; j < 8; j++) {
                float v = fmaf(-2.f, acc[i][j], ev[j]);
                if (v < bestV[i]) { bestV[i] = v; bestI[i] = s0 + tc * 8 + j; }
            }
        }
    }

    // ---- cross-thread argmin (reuse es as scratch) ----
    __syncthreads();
    float* rv = &es[0][0];
    int*   ri = (int*)&es[16][0];
    int*   cs = (int*)&es[32][0];
    #pragma unroll
    for (int i = 0; i < 8; i++) {
        int r = tr * 8 + i;
        rv[r * 16 + tc] = bestV[i];
        ri[r * 16 + tc] = bestI[i];
    }
    __syncthreads();
    if (tid < BN) {
        int r = tid;
        float bv = rv[r * 16];
        int   bi = ri[r * 16];
        #pragma unroll
        for (int t2 = 1; t2 < 16; t2++) {
            float v = rv[r * 16 + t2];
            int idx = ri[r * 16 + t2];
            if (v < bv || (v == bv && idx < bi)) { bv = v; bi = idx; }
        }
        cs[r] = bi;
        codes[n0 + r] = bi;
        atomicAdd(&counts[bi], 1.0f);
    }
    __syncthreads();

    // ---- quantized write + diff partial ----
    {
        const int r = tid & 127;
        const int h = tid >> 7;
        const int c = cs[r];
        const float4* qrow = (const float4*)(emb + (size_t)c * TD) + h * 16;
        float local = 0.f;
        #pragma unroll
        for (int k = 0; k < 16; k++) {
            float4 q4 = qrow[k];
            int d0 = h * 64 + k * 4;
            float qv[4] = {q4.x, q4.y, q4.z, q4.w};
            #pragma unroll
            for (int j = 0; j < 4; j++) {
                int d = d0 + j;
                float xv = xs[d][r];
                dout[OFF_Q + ((size_t)b * TD + d) * TT + t0 + r] = qv[j];
                float df = xv - qv[j];
                local = fmaf(df, df, local);
            }
        }
        #pragma unroll
        for (int off = 32; off; off >>= 1) local += __shfl_down(local, off, 64);
        if ((tid & 63) == 0) wsum[tid >> 6] = local;
    }

    // ---- xf transpose-out (row-major [N][D]) for the gather pass ----
    if (WRITE_XF) {
        const int r = tid >> 1;        // 0..127
        const int h = tid & 1;         // half of D
        float* dst = xf + (size_t)(n0 + r) * TD + h * 64;
        #pragma unroll
        for (int k = 0; k < 16; k++) {
            int d0 = h * 64 + k * 4;
            float4 v = make_float4(xs[d0][r], xs[d0 + 1][r], xs[d0 + 2][r], xs[d0 + 3][r]);
            *(float4*)&dst[k * 4] = v;
        }
    }

    __syncthreads();
    if (tid == 0) {
        float s2 = wsum[0] + wsum[1] + wsum[2] + wsum[3];
        atomicAdd(&dout[OFF_DIFF], s2);
    }
}

// prefix-sum of counts -> offsets/cursor; new_usage; diff scale
__global__ void vq_offsets(const float* __restrict__ usage,
                           const float* __restrict__ counts,
                           int* __restrict__ offs, int* __restrict__ cursor,
                           float* __restrict__ dout) {
    __shared__ int scan[TS];
    int i = threadIdx.x;               // one block of 1024
    int c = (int)counts[i];
    scan[i] = c;
    __syncthreads();
    for (int off = 1; off < TS; off <<= 1) {
        int v = (i >= off) ? scan[i - off] : 0;
        __syncthreads();
        scan[i] += v;
        __syncthreads();
    }
    int excl = scan[i] - c;
    offs[i] = excl;
    cursor[i] = excl;
    if (i == TS - 1) offs[TS] = scan[i];
    dout[OFF_USAGE + i] = EMA_W * usage[i] + (1.0f - EMA_W) * counts[i];
    if (i == 0) dout[OFF_DIFF] = dout[OFF_DIFF] * (1.0f / ((float)NROWS * (float)TD));
}

__global__ void vq_scatteridx(const int* __restrict__ codes,
                              int* __restrict__ cursor, int* __restrict__ rowlist) {
    int n = blockIdx.x * 256 + threadIdx.x;
    int c = codes[n];
    int pos = atomicAdd(&cursor[c], 1);
    rowlist[pos] = n;
}

template <int USE_XF>
__global__ void vq_sum(const float* __restrict__ x,
                       const float* __restrict__ xf,
                       const float* __restrict__ emb,
                       const int* __restrict__ offs,
                       const int* __restrict__ rowlist,
                       float* __restrict__ dout) {
    int s = blockIdx.x, d = threadIdx.x;   // 128 threads = dims
    int beg = offs[s], end = offs[s + 1];
    float acc = 0.f;
    for (int i = beg; i < end; i++) {
        int n = rowlist[i];
        if (USE_XF) {
            acc += xf[(size_t)n * TD + d];
        } else {
            int bb = n >> 11, t = n & (TT - 1);
            acc += x[((size_t)bb * TD + d) * TT + t];
        }
    }
    float e = emb[(size_t)s * TD + d];
    int cnt = end - beg;
    float tgt = (cnt > 0) ? (acc / (float)cnt) : e;
    dout[OFF_EMB + (size_t)s * TD + d] = EMA_W * e + (1.0f - EMA_W) * tgt;
}

extern "C" void kernel_launch(void* const* d_in, const int* in_sizes, int n_in,
                              void* d_out, int out_size, void* d_ws, size_t ws_size,
                              hipStream_t stream) {
    const float* x     = (const float*)d_in[0];
    const float* emb   = (const float*)d_in[1];
    const float* usage = (const float*)d_in[2];
    float* dout = (float*)d_out;

    float* wsf = (float*)d_ws;
    int*   wsi = (int*)d_ws;
    float* e2      = wsf + WS_E2;
    float* counts  = wsf + WS_COUNTS;
    int*   codes   = wsi + WS_CODES;
    int*   rowlist = wsi + WS_ROWLIST;
    int*   offs    = wsi + WS_OFFS;
    int*   cursor  = wsi + WS_CURSOR;
    float* embT    = wsf + WS_EMBT;
    float* xf      = wsf + WS_XF;

    const bool use_xf = ws_size >= (size_t)WS_WORDS_WITH_XF * 4;

    vq_zero<<<1, 1024, 0, stream>>>(dout, counts);
    vq_prep<<<TS, TD, 0, stream>>>(emb, e2, embT);
    if (use_xf)
        vq_main<1><<<NROWS / BN, NT, 0, stream>>>(x, emb, embT, e2, dout, counts, codes, xf);
    else
        vq_main<0><<<NROWS / BN, NT, 0, stream>>>(x, emb, embT, e2, dout, counts, codes, xf);
    vq_offsets<<<1, TS, 0, stream>>>(usage, counts, offs, cursor, dout);
    vq_scatteridx<<<NROWS / 256, 256, 0, stream>>>(codes, cursor, rowlist);
    if (use_xf)
        vq_sum<1><<<TS, TD, 0, stream>>>(x, xf, emb, offs, rowlist, dout);
    else
        vq_sum<0><<<TS, TD, 0, stream>>>(x, xf, emb, offs, rowlist, dout);
}

// Round 3
// 199.338 us; speedup vs baseline: 4.3442x; 2.7812x over previous
//
#include <hip/hip_runtime.h>

// Problem constants
#define TD 128        // D
#define TS 1024       // SIZE (codes)
#define TT 2048       // T
#define NROWS 32768   // B*T
#define BN 128        // rows per block tile
#define BS 128        // codes per LDS tile
#define NT 512        // threads per vq_main block (8 waves = 2/SIMD)
#define SPLIT 4       // blocks per code in gather-sum
#define EMA_W 0.99f

// d_out layout (flat fp32): [quantized BxDxT][diff][new_embedding SxD][new_usage S]
#define OFF_Q     0
#define OFF_DIFF  4194304
#define OFF_EMB   4194305
#define OFF_USAGE 4325377

// ws layout (units: 4-byte words)
#define WS_E2      0                       // 1024 f
#define WS_COUNTS  1024                    // 1024 f
#define WS_CODES   2048                    // 32768 i
#define WS_ROWLIST 34816                   // 32768 i
#define WS_OFFS    67584                   // 1025 i
#define WS_CURSOR  68612                   // 1024 i
#define WS_EMBT    69636                   // 131072 f (16B aligned)
#define WS_PART    200708                  // SPLIT*131072 = 524288 f (16B aligned)
#define WS_XF      724996                  // 4194304 f (16B aligned)
#define WS_WORDS_WITH_XF (WS_XF + 4194304)

__global__ void vq_zero(float* __restrict__ dout, float* __restrict__ counts) {
    int i = threadIdx.x;   // one block of 1024
    counts[i] = 0.f;
    if (i == 0) dout[OFF_DIFF] = 0.f;
}

// per code s: e2[s] = ||emb[s]||^2 ; embT[d][s] = emb[s][d]
__global__ void vq_prep(const float* __restrict__ emb,
                        float* __restrict__ e2, float* __restrict__ embT) {
    __shared__ float red[2];
    int s = blockIdx.x, d = threadIdx.x;  // 128 threads
    float v = emb[(size_t)s * TD + d];
    embT[(size_t)d * TS + s] = v;
    float sq = v * v;
    #pragma unroll
    for (int off = 32; off; off >>= 1) sq += __shfl_down(sq, off, 64);
    if ((d & 63) == 0) red[d >> 6] = sq;
    __syncthreads();
    if (d == 0) e2[s] = red[0] + red[1];
}

template <int WRITE_XF>
__launch_bounds__(NT, 2)
__global__ void vq_main(const float* __restrict__ x,
                        const float* __restrict__ emb,
                        const float* __restrict__ embT,
                        const float* __restrict__ e2,
                        float* __restrict__ dout,
                        float* __restrict__ counts,
                        int* __restrict__ codes,
                        float* __restrict__ xf) {
    __shared__ float xs[TD][BN];   // 64 KB: xs[d][r] = x[b][d][t0+r]
    __shared__ float es[TD][BS];   // 64 KB: es[d][c] = emb[s0+c][d]; reused as scratch
    __shared__ float wsum[8];

    const int tid = threadIdx.x;
    const int n0 = blockIdx.x * BN;
    const int b  = n0 >> 11;
    const int t0 = n0 & (TT - 1);

    // ---- stage x tile (coalesced along t, contiguous per wave) ----
    const float4* x4 = (const float4*)x;
    for (int k = tid; k < TD * BN / 4; k += NT) {
        int d  = k >> 5;
        int r4 = k & 31;
        float4 v = x4[((size_t)b * TD + d) * (TT / 4) + (t0 >> 2) + r4];
        *(float4*)&xs[d][r4 * 4] = v;
    }

    const int tr = tid >> 5;       // 0..15 -> 8 rows each
    const int tc = tid & 31;       // 0..31 -> 4 codes each

    float bestV[8];
    int   bestI[8];
    #pragma unroll
    for (int i = 0; i < 8; i++) { bestV[i] = 3.4e38f; bestI[i] = 0; }

    const float4* eT4 = (const float4*)embT;
    for (int tile = 0; tile < TS / BS; ++tile) {
        const int s0 = tile * BS;
        __syncthreads();
        // ---- stage embedding tile from embT (coalesced, conflict-free) ----
        for (int k = tid; k < TD * BS / 4; k += NT) {
            int d  = k >> 5;
            int c4 = k & 31;
            float4 v = eT4[(size_t)d * (TS / 4) + (s0 >> 2) + c4];
            *(float4*)&es[d][c4 * 4] = v;
        }
        __syncthreads();

        float acc[8][4];
        #pragma unroll
        for (int i = 0; i < 8; i++)
            #pragma unroll
            for (int j = 0; j < 4; j++) acc[i][j] = 0.f;

        #pragma unroll 4
        for (int d = 0; d < TD; ++d) {
            float a[8], bb[4];
            *(float4*)&a[0]  = *(const float4*)&xs[d][tr * 8];
            *(float4*)&a[4]  = *(const float4*)&xs[d][tr * 8 + 4];
            *(float4*)&bb[0] = *(const float4*)&es[d][tc * 4];
            #pragma unroll
            for (int i = 0; i < 8; i++)
                #pragma unroll
                for (int j = 0; j < 4; j++)
                    acc[i][j] = fmaf(a[i], bb[j], acc[i][j]);
        }

        // score = e2[s] - 2*dot (x^2 row-constant -> argmin-equivalent)
        float ev[4];
        *(float4*)&ev[0] = *(const float4*)&e2[s0 + tc * 4];
        #pragma unroll
        for (int i = 0; i < 8; i++) {
            #pragma unroll
            for (int j = 0; j < 4; j++) {
                float v = fmaf(-2.f, acc[i][j], ev[j]);
                if (v < bestV[i]) { bestV[i] = v; bestI[i] = s0 + tc * 4 + j; }
            }
        }
    }

    // ---- cross-thread argmin (reuse es as scratch) ----
    __syncthreads();
    float* rv = &es[0][0];             // [128][32] floats (16 KB)
    int*   ri = (int*)&es[32][0];      // [128][32] ints   (16 KB)
    int*   cs = (int*)&es[64][0];      // [128] codes
    #pragma unroll
    for (int i = 0; i < 8; i++) {
        int r = tr * 8 + i;
        rv[r * 32 + tc] = bestV[i];
        ri[r * 32 + tc] = bestI[i];
    }
    __syncthreads();
    if (tid < BN) {
        int r = tid;
        float bv = rv[r * 32];
        int   bi = ri[r * 32];
        #pragma unroll
        for (int t2 = 1; t2 < 32; t2++) {
            float v = rv[r * 32 + t2];
            int idx = ri[r * 32 + t2];
            if (v < bv || (v == bv && idx < bi)) { bv = v; bi = idx; }
        }
        cs[r] = bi;
        codes[n0 + r] = bi;
        atomicAdd(&counts[bi], 1.0f);
    }
    __syncthreads();

    // ---- quantized write + diff partial (512 threads: 128 rows x 4 dim-quarters) ----
    {
        const int r = tid & 127;
        const int q = tid >> 7;            // dim quarter (32 dims)
        const int c = cs[r];
        const float4* qrow = (const float4*)(emb + (size_t)c * TD) + q * 8;
        float local = 0.f;
        #pragma unroll
        for (int k = 0; k < 8; k++) {
            float4 q4 = qrow[k];
            int d0 = q * 32 + k * 4;
            float qv[4] = {q4.x, q4.y, q4.z, q4.w};
            #pragma unroll
            for (int j = 0; j < 4; j++) {
                int d = d0 + j;
                float xv = xs[d][r];
                dout[OFF_Q + ((size_t)b * TD + d) * TT + t0 + r] = qv[j];
                float df = xv - qv[j];
                local = fmaf(df, df, local);
            }
        }
        #pragma unroll
        for (int off = 32; off; off >>= 1) local += __shfl_down(local, off, 64);
        if ((tid & 63) == 0) wsum[tid >> 6] = local;
    }

    // ---- xf transpose-out (row-major [N][D]) for the gather pass ----
    if (WRITE_XF) {
        const int r = tid >> 2;        // 0..127
        const int q = tid & 3;         // dim quarter
        float* dst = xf + (size_t)(n0 + r) * TD + q * 32;
        #pragma unroll
        for (int k = 0; k < 8; k++) {
            int d0 = q * 32 + k * 4;
            float4 v = make_float4(xs[d0][r], xs[d0 + 1][r], xs[d0 + 2][r], xs[d0 + 3][r]);
            *(float4*)&dst[k * 4] = v;
        }
    }

    __syncthreads();
    if (tid == 0) {
        float s2 = 0.f;
        #pragma unroll
        for (int w = 0; w < 8; w++) s2 += wsum[w];
        atomicAdd(&dout[OFF_DIFF], s2);
    }
}

// prefix-sum of counts -> offsets/cursor; new_usage; diff scale
__global__ void vq_offsets(const float* __restrict__ usage,
                           const float* __restrict__ counts,
                           int* __restrict__ offs, int* __restrict__ cursor,
                           float* __restrict__ dout) {
    __shared__ int scan[TS];
    int i = threadIdx.x;               // one block of 1024
    int c = (int)counts[i];
    scan[i] = c;
    __syncthreads();
    for (int off = 1; off < TS; off <<= 1) {
        int v = (i >= off) ? scan[i - off] : 0;
        __syncthreads();
        scan[i] += v;
        __syncthreads();
    }
    int excl = scan[i] - c;
    offs[i] = excl;
    cursor[i] = excl;
    if (i == TS - 1) offs[TS] = scan[i];
    dout[OFF_USAGE + i] = EMA_W * usage[i] + (1.0f - EMA_W) * counts[i];
    if (i == 0) dout[OFF_DIFF] = dout[OFF_DIFF] * (1.0f / ((float)NROWS * (float)TD));
}

__global__ void vq_scatteridx(const int* __restrict__ codes,
                              int* __restrict__ cursor, int* __restrict__ rowlist) {
    int n = blockIdx.x * 256 + threadIdx.x;
    int c = codes[n];
    int pos = atomicAdd(&cursor[c], 1);
    rowlist[pos] = n;
}

// gather-sum: SPLIT blocks per code, 1024 threads = 8 row-groups x 128 dims.
// Each block writes its own partial slot -> no atomics, no pre-zero.
template <int USE_XF>
__global__ void vq_sum2(const float* __restrict__ x,
                        const float* __restrict__ xf,
                        const int* __restrict__ offs,
                        const int* __restrict__ rowlist,
                        float* __restrict__ part) {
    const int s  = blockIdx.x >> 2;
    const int sp = blockIdx.x & 3;
    const int g  = threadIdx.x >> 7;   // 0..7
    const int d  = threadIdx.x & 127;
    const int beg = offs[s], end = offs[s + 1];
    const int stride = SPLIT * 8;      // 32 rows in flight per code

    float a0 = 0.f, a1 = 0.f;
    int i = beg + sp * 8 + g;
    for (; i + stride < end; i += 2 * stride) {
        int n0 = rowlist[i];
        int n1 = rowlist[i + stride];
        float v0, v1;
        if (USE_XF) {
            v0 = xf[(size_t)n0 * TD + d];
            v1 = xf[(size_t)n1 * TD + d];
        } else {
            v0 = x[((size_t)(n0 >> 11) * TD + d) * TT + (n0 & (TT - 1))];
            v1 = x[((size_t)(n1 >> 11) * TD + d) * TT + (n1 & (TT - 1))];
        }
        a0 += v0; a1 += v1;
    }
    if (i < end) {
        int n0 = rowlist[i];
        a0 += USE_XF ? xf[(size_t)n0 * TD + d]
                     : x[((size_t)(n0 >> 11) * TD + d) * TT + (n0 & (TT - 1))];
    }
    float v = a0 + a1;

    __shared__ float red[1024];
    red[threadIdx.x] = v;
    __syncthreads();
    if (threadIdx.x < 512) red[threadIdx.x] += red[threadIdx.x + 512];
    __syncthreads();
    if (threadIdx.x < 256) red[threadIdx.x] += red[threadIdx.x + 256];
    __syncthreads();
    if (threadIdx.x < 128)
        part[(size_t)sp * (TS * TD) + (size_t)s * TD + d]
            = red[threadIdx.x] + red[threadIdx.x + 128];
}

// finalize: sum partials, EMA embedding
__global__ void vq_fin(const float* __restrict__ emb,
                       const float* __restrict__ counts,
                       const float* __restrict__ part,
                       float* __restrict__ dout) {
    int g = blockIdx.x * 256 + threadIdx.x;  // 0..131071
    int s = g >> 7;
    float sum = part[g] + part[TS * TD + g] + part[2 * TS * TD + g] + part[3 * TS * TD + g];
    float cnt = counts[s];
    float e = emb[g];
    float tgt = (cnt > 0.f) ? (sum / cnt) : e;
    dout[OFF_EMB + g] = EMA_W * e + (1.0f - EMA_W) * tgt;
}

extern "C" void kernel_launch(void* const* d_in, const int* in_sizes, int n_in,
                              void* d_out, int out_size, void* d_ws, size_t ws_size,
                              hipStream_t stream) {
    const float* x     = (const float*)d_in[0];
    const float* emb   = (const float*)d_in[1];
    const float* usage = (const float*)d_in[2];
    float* dout = (float*)d_out;

    float* wsf = (float*)d_ws;
    int*   wsi = (int*)d_ws;
    float* e2      = wsf + WS_E2;
    float* counts  = wsf + WS_COUNTS;
    int*   codes   = wsi + WS_CODES;
    int*   rowlist = wsi + WS_ROWLIST;
    int*   offs    = wsi + WS_OFFS;
    int*   cursor  = wsi + WS_CURSOR;
    float* embT    = wsf + WS_EMBT;
    float* part    = wsf + WS_PART;
    float* xf      = wsf + WS_XF;

    const bool use_xf = ws_size >= (size_t)WS_WORDS_WITH_XF * 4;

    vq_zero<<<1, 1024, 0, stream>>>(dout, counts);
    vq_prep<<<TS, TD, 0, stream>>>(emb, e2, embT);
    if (use_xf)
        vq_main<1><<<NROWS / BN, NT, 0, stream>>>(x, emb, embT, e2, dout, counts, codes, xf);
    else
        vq_main<0><<<NROWS / BN, NT, 0, stream>>>(x, emb, embT, e2, dout, counts, codes, xf);
    vq_offsets<<<1, TS, 0, stream>>>(usage, counts, offs, cursor, dout);
    vq_scatteridx<<<NROWS / 256, 256, 0, stream>>>(codes, cursor, rowlist);
    if (use_xf)
        vq_sum2<1><<<TS * SPLIT, 1024, 0, stream>>>(x, xf, offs, rowlist, part);
    else
        vq_sum2<0><<<TS * SPLIT, 1024, 0, stream>>>(x, xf, offs, rowlist, part);
    vq_fin<<<(TS * TD) / 256, 256, 0, stream>>>(emb, counts, part, dout);
}

// Round 4
// 156.011 us; speedup vs baseline: 5.5507x; 1.2777x over previous
//
#include <hip/hip_runtime.h>

// Problem constants
#define TD 128        // D
#define TS 1024       // SIZE (codes)
#define TT 2048       // T
#define NROWS 32768   // B*T
#define BN 128        // rows per vq_main block
#define NT 256        // threads per vq_main block (4 waves)
#define SPLIT 4       // blocks per code in gather-sum
#define EMA_W 0.99f

// d_out layout (flat fp32): [quantized BxDxT][diff][new_embedding SxD][new_usage S]
#define OFF_Q     0
#define OFF_DIFF  4194304
#define OFF_EMB   4194305
#define OFF_USAGE 4325377

// ws layout (units: 4-byte words)
#define WS_E2      0                       // 1024 f
#define WS_COUNTS  1024                    // 1024 f
#define WS_CODES   2048                    // 32768 i
#define WS_ROWLIST 34816                   // 32768 i
#define WS_OFFS    67584                   // 1025 i
#define WS_CURSOR  68612                   // 1024 i
#define WS_EHI     69636                   // 131072 f16 = 65536 words
#define WS_ELO     135172                  // 131072 f16 = 65536 words
#define WS_PART    200708                  // SPLIT*131072 = 524288 f
#define WS_XF      724996                  // 4194304 f
#define WS_WORDS_WITH_XF (WS_XF + 4194304)

typedef _Float16 f16x8 __attribute__((ext_vector_type(8)));
typedef float    f32x4 __attribute__((ext_vector_type(4)));

__global__ void vq_zero(float* __restrict__ dout, float* __restrict__ counts) {
    int i = threadIdx.x;   // one block of 1024
    counts[i] = 0.f;
    if (i == 0) dout[OFF_DIFF] = 0.f;
}

// per code s: e2[s] (fp32, matches np), plus f16 hi/lo split of emb
__global__ void vq_prep2(const float* __restrict__ emb, float* __restrict__ e2,
                         _Float16* __restrict__ ehi, _Float16* __restrict__ elo) {
    __shared__ float red[2];
    int s = blockIdx.x, d = threadIdx.x;  // 128 threads
    float v = emb[(size_t)s * TD + d];
    _Float16 h = (_Float16)v;
    ehi[(size_t)s * TD + d] = h;
    elo[(size_t)s * TD + d] = (_Float16)(v - (float)h);
    float sq = v * v;
    #pragma unroll
    for (int off = 32; off; off >>= 1) sq += __shfl_down(sq, off, 64);
    if ((d & 63) == 0) red[d >> 6] = sq;
    __syncthreads();
    if (d == 0) e2[s] = red[0] + red[1];
}

template <int WRITE_XF>
__launch_bounds__(NT, 1)
__global__ void vq_main2(const float* __restrict__ x,
                         const float* __restrict__ emb,
                         const _Float16* __restrict__ ehi,
                         const _Float16* __restrict__ elo,
                         const float* __restrict__ e2,
                         float* __restrict__ dout,
                         float* __restrict__ counts,
                         int* __restrict__ codes,
                         float* __restrict__ xf) {
    __shared__ float xs[TD][BN];      // 64 KB: xs[d][r] = x[b][d][t0+r]
    __shared__ float rv[BN * 16];     // 8 KB argmin scratch
    __shared__ int   ri[BN * 16];     // 8 KB
    __shared__ int   cs[BN];
    __shared__ float wsum[4];

    const int tid  = threadIdx.x;
    const int wid  = tid >> 6;        // wave 0..3 -> rows [wid*32, wid*32+32)
    const int lane = tid & 63;
    const int l15  = lane & 15;
    const int lk   = lane >> 4;       // 0..3 k-group
    const int n0 = blockIdx.x * BN;
    const int b  = n0 >> 11;
    const int t0 = n0 & (TT - 1);

    // ---- stage x tile into LDS (for epilogue/xf); coalesced along t ----
    const float4* x4 = (const float4*)x;
    for (int k = tid; k < TD * BN / 4; k += NT) {
        int d  = k >> 5;
        int r4 = k & 31;
        float4 v = x4[((size_t)b * TD + d) * (TT / 4) + (t0 >> 2) + r4];
        *(float4*)&xs[d][r4 * 4] = v;
    }

    // ---- A fragments (x rows, f16 hi/lo) held in registers ----
    // A-frag for 16x16x32: row = lane&15, k = (lane>>4)*8 + j
    f16x8 ah[2][4], al[2][4];
    #pragma unroll
    for (int fr = 0; fr < 2; fr++) {
        const int rt = t0 + wid * 32 + fr * 16 + l15;   // global t of this lane's A-row
        #pragma unroll
        for (int ks = 0; ks < 4; ks++) {
            const int d0 = ks * 32 + lk * 8;
            float av[8];
            #pragma unroll
            for (int j = 0; j < 8; j++)
                av[j] = x[((size_t)b * TD + d0 + j) * TT + rt];
            #pragma unroll
            for (int j = 0; j < 8; j++) {
                _Float16 h = (_Float16)av[j];
                ah[fr][ks][j] = h;
                al[fr][ks][j] = (_Float16)(av[j] - (float)h);
            }
        }
    }

    // ---- sweep 16 tiles of 64 codes; B-frags streamed from L2 ----
    float bestV[8];
    int   bestI[8];
    #pragma unroll
    for (int i = 0; i < 8; i++) { bestV[i] = 3.4e38f; bestI[i] = 0; }

    for (int tl = 0; tl < 16; ++tl) {
        f32x4 acc[2][4];
        #pragma unroll
        for (int fr = 0; fr < 2; fr++)
            #pragma unroll
            for (int fc = 0; fc < 4; fc++)
                acc[fr][fc] = (f32x4){0.f, 0.f, 0.f, 0.f};

        #pragma unroll
        for (int ks = 0; ks < 4; ks++) {
            // B-frag: col = lane&15, k = (lane>>4)*8 + j  (emb row-major = B^T)
            f16x8 bh[4], bl[4];
            #pragma unroll
            for (int fc = 0; fc < 4; fc++) {
                const size_t off = (size_t)(tl * 64 + fc * 16 + l15) * TD + ks * 32 + lk * 8;
                bh[fc] = *(const f16x8*)(ehi + off);
                bl[fc] = *(const f16x8*)(elo + off);
            }
            #pragma unroll
            for (int fc = 0; fc < 4; fc++)
                #pragma unroll
                for (int fr = 0; fr < 2; fr++) {
                    acc[fr][fc] = __builtin_amdgcn_mfma_f32_16x16x32_f16(ah[fr][ks], bh[fc], acc[fr][fc], 0, 0, 0);
                    acc[fr][fc] = __builtin_amdgcn_mfma_f32_16x16x32_f16(ah[fr][ks], bl[fc], acc[fr][fc], 0, 0, 0);
                    acc[fr][fc] = __builtin_amdgcn_mfma_f32_16x16x32_f16(al[fr][ks], bh[fc], acc[fr][fc], 0, 0, 0);
                    acc[fr][fc] = __builtin_amdgcn_mfma_f32_16x16x32_f16(al[fr][ks], bl[fc], acc[fr][fc], 0, 0, 0);
                }
        }

        // scores: e2[s] - 2*dot ; C/D layout: col = lane&15, row = (lane>>4)*4 + reg
        float e2v[4];
        #pragma unroll
        for (int fc = 0; fc < 4; fc++) e2v[fc] = e2[tl * 64 + fc * 16 + l15];
        #pragma unroll
        for (int fr = 0; fr < 2; fr++)
            #pragma unroll
            for (int i = 0; i < 4; i++)
                #pragma unroll
                for (int fc = 0; fc < 4; fc++) {
                    float sc = fmaf(-2.f, acc[fr][fc][i], e2v[fc]);
                    int slot = fr * 4 + i;
                    if (sc < bestV[slot]) { bestV[slot] = sc; bestI[slot] = tl * 64 + fc * 16 + l15; }
                }
    }

    // ---- per-lane bests -> LDS scratch [row][col-residue] ----
    #pragma unroll
    for (int fr = 0; fr < 2; fr++)
        #pragma unroll
        for (int i = 0; i < 4; i++) {
            int r = wid * 32 + fr * 16 + lk * 4 + i;
            rv[r * 16 + l15] = bestV[fr * 4 + i];
            ri[r * 16 + l15] = bestI[fr * 4 + i];
        }
    __syncthreads();

    if (tid < BN) {
        int r = tid;
        float bv = rv[r * 16];
        int   bi = ri[r * 16];
        #pragma unroll
        for (int t2 = 1; t2 < 16; t2++) {
            float v = rv[r * 16 + t2];
            int idx = ri[r * 16 + t2];
            if (v < bv || (v == bv && idx < bi)) { bv = v; bi = idx; }
        }
        cs[r] = bi;
        codes[n0 + r] = bi;
        atomicAdd(&counts[bi], 1.0f);
    }
    __syncthreads();

    // ---- epilogue: quantized write + diff partial (256 threads: 128 rows x 2 halves) ----
    {
        const int r = tid & 127;
        const int h = tid >> 7;
        const int c = cs[r];
        const float4* qrow = (const float4*)(emb + (size_t)c * TD) + h * 16;
        float local = 0.f;
        #pragma unroll
        for (int k = 0; k < 16; k++) {
            float4 q4 = qrow[k];
            int d0 = h * 64 + k * 4;
            float qv[4] = {q4.x, q4.y, q4.z, q4.w};
            #pragma unroll
            for (int j = 0; j < 4; j++) {
                int d = d0 + j;
                float xv = xs[d][r];
                dout[OFF_Q + ((size_t)b * TD + d) * TT + t0 + r] = qv[j];
                float df = xv - qv[j];
                local = fmaf(df, df, local);
            }
        }
        #pragma unroll
        for (int off = 32; off; off >>= 1) local += __shfl_down(local, off, 64);
        if ((tid & 63) == 0) wsum[tid >> 6] = local;
    }

    // ---- xf transpose-out (row-major [N][D]) for the gather pass ----
    if (WRITE_XF) {
        const int r = tid >> 1;
        const int h = tid & 1;
        float* dst = xf + (size_t)(n0 + r) * TD + h * 64;
        #pragma unroll
        for (int k = 0; k < 16; k++) {
            int d0 = h * 64 + k * 4;
            float4 v = make_float4(xs[d0][r], xs[d0 + 1][r], xs[d0 + 2][r], xs[d0 + 3][r]);
            *(float4*)&dst[k * 4] = v;
        }
    }

    __syncthreads();
    if (tid == 0) {
        float s2 = wsum[0] + wsum[1] + wsum[2] + wsum[3];
        atomicAdd(&dout[OFF_DIFF], s2);
    }
}

// prefix-sum of counts -> offsets/cursor; new_usage; diff scale
__global__ void vq_offsets(const float* __restrict__ usage,
                           const float* __restrict__ counts,
                           int* __restrict__ offs, int* __restrict__ cursor,
                           float* __restrict__ dout) {
    __shared__ int scan[TS];
    int i = threadIdx.x;               // one block of 1024
    int c = (int)counts[i];
    scan[i] = c;
    __syncthreads();
    for (int off = 1; off < TS; off <<= 1) {
        int v = (i >= off) ? scan[i - off] : 0;
        __syncthreads();
        scan[i] += v;
        __syncthreads();
    }
    int excl = scan[i] - c;
    offs[i] = excl;
    cursor[i] = excl;
    if (i == TS - 1) offs[TS] = scan[i];
    dout[OFF_USAGE + i] = EMA_W * usage[i] + (1.0f - EMA_W) * counts[i];
    if (i == 0) dout[OFF_DIFF] = dout[OFF_DIFF] * (1.0f / ((float)NROWS * (float)TD));
}

__global__ void vq_scatteridx(const int* __restrict__ codes,
                              int* __restrict__ cursor, int* __restrict__ rowlist) {
    int n = blockIdx.x * 256 + threadIdx.x;
    int c = codes[n];
    int pos = atomicAdd(&cursor[c], 1);
    rowlist[pos] = n;
}

// gather-sum: SPLIT blocks per code, 1024 threads = 8 row-groups x 128 dims.
template <int USE_XF>
__global__ void vq_sum2(const float* __restrict__ x,
                        const float* __restrict__ xf,
                        const int* __restrict__ offs,
                        const int* __restrict__ rowlist,
                        float* __restrict__ part) {
    const int s  = blockIdx.x >> 2;
    const int sp = blockIdx.x & 3;
    const int g  = threadIdx.x >> 7;   // 0..7
    const int d  = threadIdx.x & 127;
    const int beg = offs[s], end = offs[s + 1];
    const int stride = SPLIT * 8;      // 32 rows in flight per code

    float a0 = 0.f, a1 = 0.f;
    int i = beg + sp * 8 + g;
    for (; i + stride < end; i += 2 * stride) {
        int n0 = rowlist[i];
        int n1 = rowlist[i + stride];
        float v0, v1;
        if (USE_XF) {
            v0 = xf[(size_t)n0 * TD + d];
            v1 = xf[(size_t)n1 * TD + d];
        } else {
            v0 = x[((size_t)(n0 >> 11) * TD + d) * TT + (n0 & (TT - 1))];
            v1 = x[((size_t)(n1 >> 11) * TD + d) * TT + (n1 & (TT - 1))];
        }
        a0 += v0; a1 += v1;
    }
    if (i < end) {
        int n0 = rowlist[i];
        a0 += USE_XF ? xf[(size_t)n0 * TD + d]
                     : x[((size_t)(n0 >> 11) * TD + d) * TT + (n0 & (TT - 1))];
    }
    float v = a0 + a1;

    __shared__ float red[1024];
    red[threadIdx.x] = v;
    __syncthreads();
    if (threadIdx.x < 512) red[threadIdx.x] += red[threadIdx.x + 512];
    __syncthreads();
    if (threadIdx.x < 256) red[threadIdx.x] += red[threadIdx.x + 256];
    __syncthreads();
    if (threadIdx.x < 128)
        part[(size_t)sp * (TS * TD) + (size_t)s * TD + d]
            = red[threadIdx.x] + red[threadIdx.x + 128];
}

// finalize: sum partials, EMA embedding
__global__ void vq_fin(const float* __restrict__ emb,
                       const float* __restrict__ counts,
                       const float* __restrict__ part,
                       float* __restrict__ dout) {
    int g = blockIdx.x * 256 + threadIdx.x;  // 0..131071
    int s = g >> 7;
    float sum = part[g] + part[TS * TD + g] + part[2 * TS * TD + g] + part[3 * TS * TD + g];
    float cnt = counts[s];
    float e = emb[g];
    float tgt = (cnt > 0.f) ? (sum / cnt) : e;
    dout[OFF_EMB + g] = EMA_W * e + (1.0f - EMA_W) * tgt;
}

extern "C" void kernel_launch(void* const* d_in, const int* in_sizes, int n_in,
                              void* d_out, int out_size, void* d_ws, size_t ws_size,
                              hipStream_t stream) {
    const float* x     = (const float*)d_in[0];
    const float* emb   = (const float*)d_in[1];
    const float* usage = (const float*)d_in[2];
    float* dout = (float*)d_out;

    float* wsf = (float*)d_ws;
    int*   wsi = (int*)d_ws;
    float* e2      = wsf + WS_E2;
    float* counts  = wsf + WS_COUNTS;
    int*   codes   = wsi + WS_CODES;
    int*   rowlist = wsi + WS_ROWLIST;
    int*   offs    = wsi + WS_OFFS;
    int*   cursor  = wsi + WS_CURSOR;
    _Float16* ehi  = (_Float16*)(wsf + WS_EHI);
    _Float16* elo  = (_Float16*)(wsf + WS_ELO);
    float* part    = wsf + WS_PART;
    float* xf      = wsf + WS_XF;

    const bool use_xf = ws_size >= (size_t)WS_WORDS_WITH_XF * 4;

    vq_zero<<<1, 1024, 0, stream>>>(dout, counts);
    vq_prep2<<<TS, TD, 0, stream>>>(emb, e2, ehi, elo);
    if (use_xf)
        vq_main2<1><<<NROWS / BN, NT, 0, stream>>>(x, emb, ehi, elo, e2, dout, counts, codes, xf);
    else
        vq_main2<0><<<NROWS / BN, NT, 0, stream>>>(x, emb, ehi, elo, e2, dout, counts, codes, xf);
    vq_offsets<<<1, TS, 0, stream>>>(usage, counts, offs, cursor, dout);
    vq_scatteridx<<<NROWS / 256, 256, 0, stream>>>(codes, cursor, rowlist);
    if (use_xf)
        vq_sum2<1><<<TS * SPLIT, 1024, 0, stream>>>(x, xf, offs, rowlist, part);
    else
        vq_sum2<0><<<TS * SPLIT, 1024, 0, stream>>>(x, xf, offs, rowlist, part);
    vq_fin<<<(TS * TD) / 256, 256, 0, stream>>>(emb, counts, part, dout);
}